// Round 9
// baseline (333.051 us; speedup 1.0000x reference)
//
#include <hip/hip_runtime.h>
#include <math.h>

#define LRELU 0.2f
#define BSH 7                  // 128 dsts per bucket
#define BSZ (1 << BSH)
#define CH 8192                // edges per phase-1 block

typedef __attribute__((ext_vector_type(8))) short bf16x8;
typedef __attribute__((ext_vector_type(4))) float f32x4;

static __device__ __forceinline__ float bf2f(unsigned int u16) {
    union { unsigned int i; float f; } c; c.i = u16 << 16; return c.f;
}
static __device__ __forceinline__ unsigned short f2bf(float f) {
    union { float f; unsigned int i; } c; c.f = f;
    unsigned int x = c.i;
    return (unsigned short)((x + 0x7fffu + ((x >> 16) & 1u)) >> 16);  // RNE
}

// ---------------- CSR build (bucket-centric) ----------

__global__ __launch_bounds__(256) void k_bcount(const int* __restrict__ dst, int E,
                                                int NB, int* __restrict__ bcnt) {
    __shared__ int cnt[512];
    int t = threadIdx.x;
    for (int b = t; b < 512; b += 256) cnt[b] = 0;
    __syncthreads();
    int e0 = blockIdx.x * CH;
    int e1 = e0 + CH; if (e1 > E) e1 = E;
    for (int i = e0 + t; i < e1; i += 256) atomicAdd(&cnt[dst[i] >> BSH], 1);
    __syncthreads();
    for (int b = t; b < NB; b += 256) {
        int c = cnt[b];
        if (c) atomicAdd(&bcnt[b], c);
    }
}

__global__ __launch_bounds__(64) void k_bscan(const int* __restrict__ bcnt, int NB,
                                              int* __restrict__ boff,
                                              int* __restrict__ bcur) {
    int lane = threadIdx.x;
    int run = 0;
    for (int base = 0; base < NB; base += 64) {
        int v = (base + lane < NB) ? bcnt[base + lane] : 0;
        int inc = v;
#pragma unroll
        for (int off = 1; off < 64; off <<= 1) {
            int t = __shfl_up(inc, off, 64);
            if (lane >= off) inc += t;
        }
        if (base + lane < NB) {
            int e = run + inc - v;
            boff[base + lane] = e;
            bcur[base + lane] = e;
        }
        run += __shfl(inc, 63, 64);
    }
    if (lane == 0) boff[NB] = run;
}

__global__ __launch_bounds__(256) void k_binscat1(const int* __restrict__ src,
                                                  const int* __restrict__ dst,
                                                  int E, int NB,
                                                  int* __restrict__ bcur,
                                                  unsigned* __restrict__ pairs) {
    __shared__ int cnt[512];
    __shared__ int lds_d[CH];
    int t = threadIdx.x;
    int e0 = blockIdx.x * CH;
    int e1 = e0 + CH; if (e1 > E) e1 = E;
    int n = e1 - e0;
    for (int b = t; b < 512; b += 256) cnt[b] = 0;
    __syncthreads();
    for (int i = t; i < n; i += 256) {
        int d = dst[e0 + i];
        lds_d[i] = d;
        atomicAdd(&cnt[d >> BSH], 1);
    }
    __syncthreads();
    for (int b = t; b < NB; b += 256) {
        int c = cnt[b];
        cnt[b] = c ? atomicAdd(&bcur[b], c) : 0;
    }
    __syncthreads();
    for (int i = t; i < n; i += 256) {
        int d = lds_d[i];
        int p = atomicAdd(&cnt[d >> BSH], 1);
        pairs[p] = ((unsigned)src[e0 + i] << BSH) | (unsigned)(d & (BSZ - 1));
    }
}

__global__ __launch_bounds__(256) void k_bucket(const int* __restrict__ boff,
                                                const unsigned* __restrict__ pairs,
                                                int N, int* __restrict__ rowptr,
                                                int* __restrict__ col) {
    __shared__ int cnt[BSZ];
    __shared__ int cur[BSZ];
    int t = threadIdx.x;
    int b = blockIdx.x;
    int dlo = b << BSH;
    int dhi = dlo + BSZ; if (dhi > N) dhi = N;
    int nd = dhi - dlo;
    int jb = boff[b], je = boff[b + 1];
    if (t < BSZ) cnt[t] = 0;
    __syncthreads();
    for (int j = jb + t; j < je; j += 256) atomicAdd(&cnt[pairs[j] & (BSZ - 1)], 1);
    __syncthreads();
    if (t < 64) {
        int v0 = cnt[t], v1 = cnt[64 + t];
        int i0 = v0;
#pragma unroll
        for (int off = 1; off < 64; off <<= 1) {
            int q = __shfl_up(i0, off, 64);
            if (t >= off) i0 += q;
        }
        int tot0 = __shfl(i0, 63, 64);
        int i1 = v1;
#pragma unroll
        for (int off = 1; off < 64; off <<= 1) {
            int q = __shfl_up(i1, off, 64);
            if (t >= off) i1 += q;
        }
        int e0x = jb + i0 - v0;
        int e1x = jb + tot0 + i1 - v1;
        cur[t] = e0x;
        cur[64 + t] = e1x;
        if (t < nd) rowptr[dlo + t] = e0x;
        if (64 + t < nd) rowptr[dlo + 64 + t] = e1x;
        if (t == 0 && dhi == N) rowptr[N] = je;
    }
    __syncthreads();
    for (int j = jb + t; j < je; j += 256) {
        unsigned pk = pairs[j];
        int p = atomicAdd(&cur[pk & (BSZ - 1)], 1);
        col[p] = (int)(pk >> BSH);
    }
}

// ---------------- weight convert/transpose to bf16 ----------------
__global__ __launch_bounds__(256) void k_cvtW(const float* __restrict__ W1,
                                              const float* __restrict__ W2,
                                              unsigned short* __restrict__ Wt1,
                                              unsigned short* __restrict__ Wt2) {
    int idx = blockIdx.x * 256 + threadIdx.x;
    if (idx < 16384) {
        int n = idx >> 8, k = idx & 255;
        Wt1[idx] = f2bf(W1[k * 64 + n]);
    } else if (idx < 16384 + 4096) {
        int j = idx - 16384;
        int n = j >> 6, k = j & 63;
        Wt2[j] = f2bf(W2[k * 64 + n]);
    }
}

// ---------------- MFMA GEMM1 (writes H as two half-tables [2][N][32]) -------
__global__ __launch_bounds__(256) void k_gemm1m(const float* __restrict__ X,
                                                const unsigned short* __restrict__ Wt,
                                                const float* __restrict__ atts,
                                                const float* __restrict__ attd,
                                                int N, unsigned short* __restrict__ Hb,
                                                float* __restrict__ asrc,
                                                float* __restrict__ adst) {
    __shared__ short Xl[64 * 256];
    int t = threadIdx.x, l = t & 63, w = t >> 6;
    int rblk = blockIdx.x * 64;

    int half = l >> 5;
    int c8 = (l & 31) * 8;
#pragma unroll
    for (int i = 0; i < 8; ++i) {
        int rl = w * 16 + i * 2 + half;
        int row = rblk + rl;
        float4 x0 = {0.f, 0.f, 0.f, 0.f}, x1 = {0.f, 0.f, 0.f, 0.f};
        if (row < N) {
            x0 = *reinterpret_cast<const float4*>(X + (size_t)row * 256 + c8);
            x1 = *reinterpret_cast<const float4*>(X + (size_t)row * 256 + c8 + 4);
        }
        bf16x8 p;
        p[0] = (short)f2bf(x0.x); p[1] = (short)f2bf(x0.y);
        p[2] = (short)f2bf(x0.z); p[3] = (short)f2bf(x0.w);
        p[4] = (short)f2bf(x1.x); p[5] = (short)f2bf(x1.y);
        p[6] = (short)f2bf(x1.z); p[7] = (short)f2bf(x1.w);
        int g = (l & 31) ^ (rl & 7);
        *reinterpret_cast<bf16x8*>(&Xl[rl * 256 + g * 8]) = p;
    }

    int m = l & 15, quad = l >> 4;
    int rl = w * 16 + m;
    f32x4 acc0 = {0.f, 0.f, 0.f, 0.f}, acc1 = acc0, acc2 = acc0, acc3 = acc0;
#pragma unroll
    for (int tt = 0; tt < 8; ++tt) {
        int g = (tt * 4 + quad) ^ (m & 7);
        bf16x8 a = *reinterpret_cast<const bf16x8*>(&Xl[rl * 256 + g * 8]);
        int kk = tt * 32 + quad * 8;
        bf16x8 b0 = *reinterpret_cast<const bf16x8*>(&Wt[(0 * 16 + m) * 256 + kk]);
        bf16x8 b1 = *reinterpret_cast<const bf16x8*>(&Wt[(1 * 16 + m) * 256 + kk]);
        bf16x8 b2 = *reinterpret_cast<const bf16x8*>(&Wt[(2 * 16 + m) * 256 + kk]);
        bf16x8 b3 = *reinterpret_cast<const bf16x8*>(&Wt[(3 * 16 + m) * 256 + kk]);
        acc0 = __builtin_amdgcn_mfma_f32_16x16x32_bf16(a, b0, acc0, 0, 0, 0);
        acc1 = __builtin_amdgcn_mfma_f32_16x16x32_bf16(a, b1, acc1, 0, 0, 0);
        acc2 = __builtin_amdgcn_mfma_f32_16x16x32_bf16(a, b2, acc2, 0, 0, 0);
        acc3 = __builtin_amdgcn_mfma_f32_16x16x32_bf16(a, b3, acc3, 0, 0, 0);
    }

    int r0 = rblk + w * 16;
    f32x4 accs[4] = {acc0, acc1, acc2, acc3};
#pragma unroll
    for (int nt = 0; nt < 4; ++nt) {
        int cn = nt * 16 + m;
        int pz = cn >> 5, cl = cn & 31;
        float av_s = atts[cn], av_d = attd[cn];
#pragma unroll
        for (int r = 0; r < 4; ++r) {
            int row = r0 + quad * 4 + r;
            float hv = accs[nt][r];
            if (row < N)
                Hb[(size_t)pz * N * 32 + (size_t)row * 32 + cl] = f2bf(hv);
            float vs = hv * av_s, vd = hv * av_d;
            vs += __shfl_xor(vs, 1, 64); vs += __shfl_xor(vs, 2, 64); vs += __shfl_xor(vs, 4, 64);
            vd += __shfl_xor(vd, 1, 64); vd += __shfl_xor(vd, 2, 64); vd += __shfl_xor(vd, 4, 64);
            if ((m & 7) == 0 && row < N) {
                int head = cn >> 3;
                asrc[row * 8 + head] = vs;
                adst[row * 8 + head] = vd;
            }
        }
    }
}

// ---------------- MFMA GEMM2 (writes G as two half-tables [2][N][32]) -------
__global__ __launch_bounds__(256) void k_gemm2m(const unsigned short* __restrict__ Xb,
                                                const unsigned short* __restrict__ Wt,
                                                const float* __restrict__ atts,
                                                const float* __restrict__ attd,
                                                int N, unsigned short* __restrict__ Gb,
                                                float* __restrict__ asrc,
                                                float* __restrict__ adst) {
    int t = threadIdx.x, l = t & 63, w = t >> 6;
    int rblk = blockIdx.x * 64;
    int m = l & 15, quad = l >> 4;
    int row = rblk + w * 16 + m;
    int rowc = (row < N) ? row : 0;

    f32x4 acc0 = {0.f, 0.f, 0.f, 0.f}, acc1 = acc0, acc2 = acc0, acc3 = acc0;
#pragma unroll
    for (int tt = 0; tt < 2; ++tt) {
        int kk = tt * 32 + quad * 8;
        bf16x8 a = *reinterpret_cast<const bf16x8*>(&Xb[(size_t)rowc * 64 + kk]);
        bf16x8 b0 = *reinterpret_cast<const bf16x8*>(&Wt[(0 * 16 + m) * 64 + kk]);
        bf16x8 b1 = *reinterpret_cast<const bf16x8*>(&Wt[(1 * 16 + m) * 64 + kk]);
        bf16x8 b2 = *reinterpret_cast<const bf16x8*>(&Wt[(2 * 16 + m) * 64 + kk]);
        bf16x8 b3 = *reinterpret_cast<const bf16x8*>(&Wt[(3 * 16 + m) * 64 + kk]);
        acc0 = __builtin_amdgcn_mfma_f32_16x16x32_bf16(a, b0, acc0, 0, 0, 0);
        acc1 = __builtin_amdgcn_mfma_f32_16x16x32_bf16(a, b1, acc1, 0, 0, 0);
        acc2 = __builtin_amdgcn_mfma_f32_16x16x32_bf16(a, b2, acc2, 0, 0, 0);
        acc3 = __builtin_amdgcn_mfma_f32_16x16x32_bf16(a, b3, acc3, 0, 0, 0);
    }

    int r0 = rblk + w * 16;
    f32x4 accs[4] = {acc0, acc1, acc2, acc3};
#pragma unroll
    for (int r = 0; r < 4; ++r) {
        int orow = r0 + quad * 4 + r;
        float vs = 0.f, vd = 0.f;
#pragma unroll
        for (int nt = 0; nt < 4; ++nt) {
            int cn = nt * 16 + m;
            int pz = cn >> 5, cl = cn & 31;
            float hv = accs[nt][r];
            if (orow < N)
                Gb[(size_t)pz * N * 32 + (size_t)orow * 32 + cl] = f2bf(hv);
            vs = fmaf(hv, atts[cn], vs);
            vd = fmaf(hv, attd[cn], vd);
        }
#pragma unroll
        for (int off = 1; off < 16; off <<= 1) {
            vs += __shfl_xor(vs, off, 64);
            vd += __shfl_xor(vd, off, 64);
        }
        if (m == 0 && orow < N) { asrc[orow] = vs; adst[orow] = vd; }
    }
}

// ------- Gather pass: 32 channels (half-table, 3.2 MB -> L2-resident) -------
// lane = g*4 + sub.  g = edge slot (16 in flight), sub = channel octet (of 4).
// Layer 1: head = p*4+sub handled exactly (denoms per-head). Pointers pre-offset.

__global__ __launch_bounds__(256) void k_gather1p(const int* __restrict__ rowptr,
                                                  const int* __restrict__ col,
                                                  const uint4* __restrict__ Hp,   // half-table, 4 uint4/row
                                                  const float* __restrict__ asrcp, // +p*4
                                                  const float* __restrict__ adstp, // +p*4
                                                  const float* __restrict__ biasp, // +p*32
                                                  int N, unsigned short* __restrict__ outp) { // +p*32, stride 64
    int lane = threadIdx.x & 63;
    int d = (blockIdx.x << 2) + (threadIdx.x >> 6);
    if (d >= N) return;
    int g = lane >> 2;        // 16 edge slots
    int sub = lane & 3;       // head within pass / channel octet
    float adv = adstp[d * 8 + sub];
    int jb = rowptr[d], je = rowptr[d + 1];

    float acc[8] = {0.f, 0.f, 0.f, 0.f, 0.f, 0.f, 0.f, 0.f};
    float denom = 0.f;
#pragma unroll 2
    for (int u = jb + g; u < je; u += 16) {
        int s = col[u];
        float e = asrcp[s * 8 + sub] + adv;
        e = (e > 0.f) ? e : LRELU * e;
        float w = __expf(e);
        uint4 hv = Hp[(size_t)s * 4 + sub];
        denom += w;
        acc[0] = fmaf(w, bf2f(hv.x & 0xffffu), acc[0]);
        acc[1] = fmaf(w, bf2f(hv.x >> 16), acc[1]);
        acc[2] = fmaf(w, bf2f(hv.y & 0xffffu), acc[2]);
        acc[3] = fmaf(w, bf2f(hv.y >> 16), acc[3]);
        acc[4] = fmaf(w, bf2f(hv.z & 0xffffu), acc[4]);
        acc[5] = fmaf(w, bf2f(hv.z >> 16), acc[5]);
        acc[6] = fmaf(w, bf2f(hv.w & 0xffffu), acc[6]);
        acc[7] = fmaf(w, bf2f(hv.w >> 16), acc[7]);
    }
#pragma unroll
    for (int off = 4; off < 64; off <<= 1) {
#pragma unroll
        for (int c = 0; c < 8; ++c) acc[c] += __shfl_xor(acc[c], off, 64);
        denom += __shfl_xor(denom, off, 64);
    }
    if (lane < 4) {
        float invd = 1.f / (denom + 1e-16f);
        unsigned short pk[8];
#pragma unroll
        for (int c = 0; c < 8; ++c) {
            float v = fmaf(acc[c], invd, biasp[sub * 8 + c]);
            v = (v > 0.f) ? v : expm1f(v);
            pk[c] = f2bf(v);
        }
        uint4 pv;
        pv.x = (unsigned)pk[0] | ((unsigned)pk[1] << 16);
        pv.y = (unsigned)pk[2] | ((unsigned)pk[3] << 16);
        pv.z = (unsigned)pk[4] | ((unsigned)pk[5] << 16);
        pv.w = (unsigned)pk[6] | ((unsigned)pk[7] << 16);
        *reinterpret_cast<uint4*>(&outp[(size_t)d * 64 + sub * 8]) = pv;
    }
}

// Layer 2 pass: single head (w shared by all channels); writes raw v to out.
__global__ __launch_bounds__(256) void k_gather2p(const int* __restrict__ rowptr,
                                                  const int* __restrict__ col,
                                                  const uint4* __restrict__ Gp,   // half-table
                                                  const float* __restrict__ asrc,
                                                  const float* __restrict__ adst,
                                                  const float* __restrict__ biasp, // +p*32
                                                  int N, float* __restrict__ outp) { // +p*32, stride 64
    int lane = threadIdx.x & 63;
    int d = (blockIdx.x << 2) + (threadIdx.x >> 6);
    if (d >= N) return;
    int g = lane >> 2;
    int sub = lane & 3;
    float adv = adst[d];
    int jb = rowptr[d], je = rowptr[d + 1];

    float acc[8] = {0.f, 0.f, 0.f, 0.f, 0.f, 0.f, 0.f, 0.f};
    float denom = 0.f;
#pragma unroll 2
    for (int u = jb + g; u < je; u += 16) {
        int s = col[u];
        float e = asrc[s] + adv;
        e = (e > 0.f) ? e : LRELU * e;
        float w = __expf(e);
        uint4 hv = Gp[(size_t)s * 4 + sub];
        denom += w;
        acc[0] = fmaf(w, bf2f(hv.x & 0xffffu), acc[0]);
        acc[1] = fmaf(w, bf2f(hv.x >> 16), acc[1]);
        acc[2] = fmaf(w, bf2f(hv.y & 0xffffu), acc[2]);
        acc[3] = fmaf(w, bf2f(hv.y >> 16), acc[3]);
        acc[4] = fmaf(w, bf2f(hv.z & 0xffffu), acc[4]);
        acc[5] = fmaf(w, bf2f(hv.z >> 16), acc[5]);
        acc[6] = fmaf(w, bf2f(hv.w & 0xffffu), acc[6]);
        acc[7] = fmaf(w, bf2f(hv.w >> 16), acc[7]);
    }
#pragma unroll
    for (int off = 4; off < 64; off <<= 1) {
#pragma unroll
        for (int c = 0; c < 8; ++c) acc[c] += __shfl_xor(acc[c], off, 64);
        denom += __shfl_xor(denom, off, 64);
    }
    if (lane < 4) {
        float invd = 1.f / (denom + 1e-16f);
        float4 o0, o1;
        o0.x = fmaf(acc[0], invd, biasp[sub * 8 + 0]);
        o0.y = fmaf(acc[1], invd, biasp[sub * 8 + 1]);
        o0.z = fmaf(acc[2], invd, biasp[sub * 8 + 2]);
        o0.w = fmaf(acc[3], invd, biasp[sub * 8 + 3]);
        o1.x = fmaf(acc[4], invd, biasp[sub * 8 + 4]);
        o1.y = fmaf(acc[5], invd, biasp[sub * 8 + 5]);
        o1.z = fmaf(acc[6], invd, biasp[sub * 8 + 6]);
        o1.w = fmaf(acc[7], invd, biasp[sub * 8 + 7]);
        *reinterpret_cast<float4*>(&outp[(size_t)d * 64 + sub * 8]) = o0;
        *reinterpret_cast<float4*>(&outp[(size_t)d * 64 + sub * 8 + 4]) = o1;
    }
}

// log_softmax over each row of 64 (one wave per row).
__global__ __launch_bounds__(256) void k_lsm(float* __restrict__ out, int N) {
    int lane = threadIdx.x & 63;
    int d = (blockIdx.x << 2) + (threadIdx.x >> 6);
    if (d >= N) return;
    float v = out[(size_t)d * 64 + lane];
    float m = v;
#pragma unroll
    for (int off = 1; off < 64; off <<= 1) m = fmaxf(m, __shfl_xor(m, off, 64));
    float se = __expf(v - m);
#pragma unroll
    for (int off = 1; off < 64; off <<= 1) se += __shfl_xor(se, off, 64);
    out[(size_t)d * 64 + lane] = v - m - __logf(se);
}

// ---------------- launch ----------------

extern "C" void kernel_launch(void* const* d_in, const int* in_sizes, int n_in,
                              void* d_out, int out_size, void* d_ws, size_t ws_size,
                              hipStream_t stream) {
    const float* x   = (const float*)d_in[0];
    const int*   ei  = (const int*)d_in[1];
    const float* W1  = (const float*)d_in[2];
    const float* as1 = (const float*)d_in[3];
    const float* ad1 = (const float*)d_in[4];
    const float* b1  = (const float*)d_in[5];
    const float* W2  = (const float*)d_in[6];
    const float* as2 = (const float*)d_in[7];
    const float* ad2 = (const float*)d_in[8];
    const float* b2  = (const float*)d_in[9];
    float* out = (float*)d_out;

    const int N = in_sizes[0] / 256;
    const int E = in_sizes[1] / 2;
    const int* src = ei;
    const int* dst = ei + E;
    const int NB = (N + BSZ - 1) >> BSH;
    const int nchunk = (E + CH - 1) / CH;

    char* ws = (char*)d_ws;
    size_t off = 0;
    auto alloc = [&](size_t bytes) -> void* {
        void* p = ws + off;
        off = (off + bytes + 255) & ~(size_t)255;
        return p;
    };
    int*      bcnt   = (int*)alloc((size_t)NB * 4);
    int*      boff   = (int*)alloc((size_t)(NB + 1) * 4);
    int*      bcur   = (int*)alloc((size_t)NB * 4);
    int*      rowptr = (int*)alloc((size_t)(N + 1) * 4);
    int*      col    = (int*)alloc((size_t)E * 4);
    unsigned* pairs  = (unsigned*)alloc((size_t)E * 4);
    unsigned short* wt1 = (unsigned short*)alloc(64 * 256 * 2);
    unsigned short* wt2 = (unsigned short*)alloc(64 * 64 * 2);
    unsigned short* h1b = (unsigned short*)alloc((size_t)N * 64 * 2);  // [2][N][32]
    float* a_s1   = (float*)alloc((size_t)N * 8 * 4);
    float* a_d1   = (float*)alloc((size_t)N * 8 * 4);
    unsigned short* h2b = (unsigned short*)alloc((size_t)N * 64 * 2);  // full rows
    unsigned short* gb  = (unsigned short*)alloc((size_t)N * 64 * 2);  // [2][N][32]
    float* a_s2   = (float*)alloc((size_t)N * 4);
    float* a_d2   = (float*)alloc((size_t)N * 4);
    (void)ws_size; (void)n_in; (void)out_size;

    k_cvtW<<<80, 256, 0, stream>>>(W1, W2, wt1, wt2);

    hipMemsetAsync(bcnt, 0, (size_t)NB * 4, stream);
    k_bcount<<<nchunk, 256, 0, stream>>>(dst, E, NB, bcnt);
    k_bscan<<<1, 64, 0, stream>>>(bcnt, NB, boff, bcur);
    k_binscat1<<<nchunk, 256, 0, stream>>>(src, dst, E, NB, bcur, pairs);
    k_bucket<<<NB, 256, 0, stream>>>(boff, pairs, N, rowptr, col);

    int gblk = (N + 63) / 64;
    k_gemm1m<<<gblk, 256, 0, stream>>>(x, wt1, as1, ad1, N, h1b, a_s1, a_d1);

    int gather_blocks = (N + 3) / 4;
    for (int p = 0; p < 2; ++p) {
        k_gather1p<<<gather_blocks, 256, 0, stream>>>(
            rowptr, col,
            (const uint4*)(h1b + (size_t)p * N * 32),
            a_s1 + p * 4, a_d1 + p * 4, b1 + p * 32,
            N, h2b + p * 32);
    }

    k_gemm2m<<<gblk, 256, 0, stream>>>(h2b, wt2, as2, ad2, N, gb, a_s2, a_d2);

    for (int p = 0; p < 2; ++p) {
        k_gather2p<<<gather_blocks, 256, 0, stream>>>(
            rowptr, col,
            (const uint4*)(gb + (size_t)p * N * 32),
            a_s2, a_d2, b2 + p * 32,
            N, out + p * 32);
    }
    k_lsm<<<gather_blocks, 256, 0, stream>>>(out, N);
}